// Round 12
// baseline (238.441 us; speedup 1.0000x reference)
//
#include <hip/hip_runtime.h>
#include <hip/hip_bf16.h>
#include <cstdint>

#define HWS 3136
#define WID 56
#define NKQ 307328.0f   // 2 * 49 * 3136
#define X3SCALE 2048.0f
#define X3INV   (1.0f / 2048.0f)
#define WQ      65535.0f

// f32 parameter block ("small", at ws byte offset 512), element offsets:
#define S_CW1 0      // 288  (16x18)
#define S_CW2 288    // 512  (32x16)
#define S_CB2 800    // 32
#define S_WP  832    // 4
#define S_G1  836    // 18
#define S_BE1 854    // 18
#define S_G2  872    // 16
#define S_BE2 888    // 16
#define S_TOT 904

__device__ __forceinline__ int refl(int i) {
  if (i < 0) i = -i;
  if (i >= WID) i = 2 * WID - 2 - i;
  return i;
}

// ---------------------------------------------------------------------------
// Kernel 0: pack small params to the f32 block (parallel).
// ---------------------------------------------------------------------------
__global__ __launch_bounds__(256) void k_prep(
    const float* __restrict__ cw1, const float* __restrict__ cw2,
    const float* __restrict__ cb2, const float* __restrict__ wp,
    const float* __restrict__ g1, const float* __restrict__ be1,
    const float* __restrict__ g2, const float* __restrict__ be2,
    float* __restrict__ small)
{
  int e = blockIdx.x * 256 + threadIdx.x;
  if (e >= S_TOT) return;
  float v;
  if (e < S_CW2)      v = cw1[e];
  else if (e < S_CB2) v = cw2[e - S_CW2];
  else if (e < S_WP)  v = cb2[e - S_CB2];
  else if (e < S_G1)  v = wp [e - S_WP];
  else if (e < S_BE1) v = g1 [e - S_G1];
  else if (e < S_G2)  v = be1[e - S_BE1];
  else if (e < S_BE2) v = g2 [e - S_G2];
  else                v = be2[e - S_BE2];
  small[e] = v;
}

// ---------------------------------------------------------------------------
// Kernel 1 v2: register-tiled projections. 196 blocks x 128 threads.
// Block: 32 pixels, all 288 rows. Thread: 9 rows x 8 pixels (72 acc).
// x staged once in xs[256][32] (broadcast reads); weights streamed through
// LDS in 16-column chunks, transposed to 16B-aligned 9-row fragments.
// Same fmaf order per output as r11 -> bit-identical results.
// ---------------------------------------------------------------------------
__global__ __launch_bounds__(128) void k_proj(
    const float* __restrict__ x,
    const float* __restrict__ w1, const float* __restrict__ b1,
    const float* __restrict__ w2, const float* __restrict__ b2,
    const float* __restrict__ w3, const float* __restrict__ b3,
    float* __restrict__ x1t, float* __restrict__ x2t, short* __restrict__ x3i)
{
  __shared__ float xs[256][32];        // 32 KB
  __shared__ float wc[16][32][12];     // 24 KB: [chunk-col j][rowtile t][0..8]
  const int tid = threadIdx.x;
  const int n  = blockIdx.x / 98;
  const int q0 = (blockIdx.x % 98) * 32;
  const int t  = tid & 31;             // row tile: rows 9t .. 9t+8
  const int p0 = (tid >> 5) * 8;       // pixel group: 8 px

  // stage x[n, :, q0..q0+31]
  for (int e = tid; e < 2048; e += 128) {
    int c = e >> 3, p4 = (e & 7) * 4;
    float4 f = *(const float4*)(x + (size_t)(n * 256 + c) * HWS + q0 + p4);
    xs[c][p4 + 0] = f.x; xs[c][p4 + 1] = f.y;
    xs[c][p4 + 2] = f.z; xs[c][p4 + 3] = f.w;
  }

  float acc[9][8];
  #pragma unroll
  for (int i = 0; i < 9; i++) {
    int r = 9 * t + i;
    float bias = (r < 16) ? b1[r] : (r < 32) ? b2[r - 16] : b3[r - 32];
    #pragma unroll
    for (int p = 0; p < 8; p++) acc[i][p] = bias;
  }

  for (int ch = 0; ch < 16; ch++) {
    __syncthreads();   // xs ready (iter 0) / previous compute done
    const int c0 = ch * 16;
    // stage weight chunk (columns c0..c0+15, all 288 rows), transposed
    for (int e = tid; e < 1152; e += 128) {
      int row = e >> 2, jq = (e & 3) * 4;
      const float* src;
      if (row < 16)      src = w1 + row * 256;
      else if (row < 32) src = w2 + (row - 16) * 256;
      else               src = w3 + (row - 32) * 256;
      float4 f = *(const float4*)(src + c0 + jq);
      int tt = row / 9, ii = row - tt * 9;
      wc[jq + 0][tt][ii] = f.x;
      wc[jq + 1][tt][ii] = f.y;
      wc[jq + 2][tt][ii] = f.z;
      wc[jq + 3][tt][ii] = f.w;
    }
    __syncthreads();
    #pragma unroll
    for (int j = 0; j < 16; j++) {
      float w9[9], x8[8];
      #pragma unroll
      for (int i = 0; i < 9; i++) w9[i] = wc[j][t][i];
      const float* xr = &xs[c0 + j][p0];
      #pragma unroll
      for (int p = 0; p < 8; p++) x8[p] = xr[p];
      #pragma unroll
      for (int i = 0; i < 9; i++)
        #pragma unroll
        for (int p = 0; p < 8; p++)
          acc[i][p] = fmaf(w9[i], x8[p], acc[i][p]);
    }
  }

  // stores
  #pragma unroll
  for (int i = 0; i < 9; i++) {
    int r = 9 * t + i;
    if (r < 16) {
      #pragma unroll
      for (int p = 0; p < 8; p++)
        x1t[(size_t)(n * HWS + q0 + p0 + p) * 16 + r] = acc[i][p];
    } else if (r < 32) {
      #pragma unroll
      for (int p = 0; p < 8; p++)
        x2t[(size_t)(n * HWS + q0 + p0 + p) * 16 + (r - 16)] = acc[i][p];
    } else {
      #pragma unroll
      for (int p = 0; p < 8; p++) {
        float cl = fminf(fmaxf(acc[i][p], -15.9f), 15.9f);
        x3i[(size_t)(n * HWS + q0 + p0 + p) * 256 + (r - 32)] =
            (short)__float2int_rn(cl * X3SCALE);
      }
    }
  }
}

// ---------------------------------------------------------------------------
// Kernel 2: BN1 statistics (18 channels), 392 blocks + atomics.
// ---------------------------------------------------------------------------
__global__ __launch_bounds__(256) void k_stats1(
    const float* __restrict__ x1t, const float* __restrict__ x2t,
    const float* __restrict__ small, float* __restrict__ gsum1)
{
  __shared__ float red[4][36];
  const int tid = threadIdx.x;
  const int bid = blockIdx.x;
  const int n = bid / 196;
  const int r = bid % 196;
  const int k = r >> 2, quar = r & 3;
  const int ki = k / 7 - 3, kj = k % 7 - 3;
  const float wp00 = small[S_WP+0], wp01 = small[S_WP+1];
  const float wp10 = small[S_WP+2], wp11 = small[S_WP+3];
  float s[18], ss[18];
  #pragma unroll
  for (int i = 0; i < 18; i++) { s[i] = 0.f; ss[i] = 0.f; }

  for (int qq = tid; qq < 784; qq += 256) {
    int q = quar * 784 + qq;
    int y = q / WID, xx = q - y * WID;
    int ny = refl(y + ki), nx = refl(xx + kj);
    int nb = ny * WID + nx;
    const float4* a = (const float4*)(x1t + (size_t)(n * HWS + q) * 16);
    const float4* b = (const float4*)(x2t + (size_t)(n * HWS + nb) * 16);
    #pragma unroll
    for (int r4 = 0; r4 < 4; r4++) {
      float4 av = a[r4], bv = b[r4];
      float v;
      v = av.x - bv.x; s[r4*4+0] += v; ss[r4*4+0] += v * v;
      v = av.y - bv.y; s[r4*4+1] += v; ss[r4*4+1] += v * v;
      v = av.z - bv.z; s[r4*4+2] += v; ss[r4*4+2] += v * v;
      v = av.w - bv.w; s[r4*4+3] += v; ss[r4*4+3] += v * v;
    }
    float dlw = (float)(xx - nx) * (2.f / 55.f);
    float dlh = (float)(y - ny) * (2.f / 55.f);
    float v16 = wp00 * dlw + wp01 * dlh;
    float v17 = wp10 * dlw + wp11 * dlh;
    s[16] += v16; ss[16] += v16 * v16;
    s[17] += v17; ss[17] += v17 * v17;
  }

  #pragma unroll
  for (int i = 0; i < 18; i++) {
    #pragma unroll
    for (int off = 32; off > 0; off >>= 1) {
      s[i]  += __shfl_down(s[i], off);
      ss[i] += __shfl_down(ss[i], off);
    }
  }
  const int wvv = tid >> 6, lane = tid & 63;
  if (lane == 0) {
    #pragma unroll
    for (int i = 0; i < 18; i++) { red[wvv][i] = s[i]; red[wvv][18 + i] = ss[i]; }
  }
  __syncthreads();
  if (tid < 36) {
    float t = red[0][tid] + red[1][tid] + red[2][tid] + red[3][tid];
    atomicAdd(&gsum1[tid], t);
  }
}

// ---------------------------------------------------------------------------
// Kernel 3: BN2 statistics (16 channels), 392 blocks + atomics.
// ---------------------------------------------------------------------------
__global__ __launch_bounds__(256) void k_stats2(
    const float* __restrict__ x1t, const float* __restrict__ x2t,
    const float* __restrict__ small,
    const float* __restrict__ gsum1, float* __restrict__ gsum2)
{
  __shared__ float red[4][32];
  const int tid = threadIdx.x;
  const float inv = 1.f / NKQ;
  float sc1r[18], sh1r[18];
  #pragma unroll
  for (int c = 0; c < 18; c++) {
    float m = gsum1[c] * inv;
    float var = gsum1[18 + c] * inv - m * m;
    float sc = small[S_G1 + c] * rsqrtf(var + 1e-5f);
    sc1r[c] = sc; sh1r[c] = small[S_BE1 + c] - m * sc;
  }

  const int bid = blockIdx.x;
  const int n = bid / 196;
  const int r = bid % 196;
  const int k = r >> 2, quar = r & 3;
  const int ki = k / 7 - 3, kj = k % 7 - 3;
  const float wp00 = small[S_WP+0], wp01 = small[S_WP+1];
  const float wp10 = small[S_WP+2], wp11 = small[S_WP+3];
  const float* cw1f = small + S_CW1;
  float s[16], ss[16];
  #pragma unroll
  for (int i = 0; i < 16; i++) { s[i] = 0.f; ss[i] = 0.f; }

  for (int qq = tid; qq < 784; qq += 256) {
    int q = quar * 784 + qq;
    int y = q / WID, xx = q - y * WID;
    int ny = refl(y + ki), nx = refl(xx + kj);
    int nb = ny * WID + nx;
    float t1v[18];
    const float4* a4 = (const float4*)(x1t + (size_t)(n * HWS + q) * 16);
    const float4* b4 = (const float4*)(x2t + (size_t)(n * HWS + nb) * 16);
    #pragma unroll
    for (int r4 = 0; r4 < 4; r4++) {
      float4 av = a4[r4], bv = b4[r4];
      t1v[r4*4+0] = av.x - bv.x; t1v[r4*4+1] = av.y - bv.y;
      t1v[r4*4+2] = av.z - bv.z; t1v[r4*4+3] = av.w - bv.w;
    }
    float dlw = (float)(xx - nx) * (2.f / 55.f);
    float dlh = (float)(y - ny) * (2.f / 55.f);
    t1v[16] = wp00 * dlw + wp01 * dlh;
    t1v[17] = wp10 * dlw + wp11 * dlh;
    #pragma unroll
    for (int c = 0; c < 18; c++) t1v[c] = fmaxf(fmaf(t1v[c], sc1r[c], sh1r[c]), 0.f);
    #pragma unroll
    for (int r2 = 0; r2 < 16; r2++) {
      float acc = 0.f;
      #pragma unroll
      for (int c = 0; c < 18; c++) acc = fmaf(cw1f[r2 * 18 + c], t1v[c], acc);
      s[r2] += acc; ss[r2] += acc * acc;
    }
  }

  #pragma unroll
  for (int i = 0; i < 16; i++) {
    #pragma unroll
    for (int off = 32; off > 0; off >>= 1) {
      s[i]  += __shfl_down(s[i], off);
      ss[i] += __shfl_down(ss[i], off);
    }
  }
  const int wvv = tid >> 6, lane = tid & 63;
  if (lane == 0) {
    #pragma unroll
    for (int i = 0; i < 16; i++) { red[wvv][i] = s[i]; red[wvv][16 + i] = ss[i]; }
  }
  __syncthreads();
  if (tid < 32) {
    float t = red[0][tid] + red[1][tid] + red[2][tid] + red[3][tid];
    atomicAdd(&gsum2[tid], t);
  }
}

// ---------------------------------------------------------------------------
// Kernel 4: 4 waves/block, one wave per pixel, grid 1568. f32 NCHW output.
// (unchanged from r11 except float4 x1t/x2t loads)
// ---------------------------------------------------------------------------
__global__ __launch_bounds__(256) void k_final(
    const float* __restrict__ x1t, const float* __restrict__ x2t,
    const short* __restrict__ x3i, const float* __restrict__ small,
    const float* __restrict__ gsum1, const float* __restrict__ gsum2,
    float* __restrict__ outf)
{
  __shared__ unsigned short wws[4][49][34];
  __shared__ int nbs[4][49];
  __shared__ float sc1s[18], sh1s[18], sc2s[16], sh2s[16];

  const int tid = threadIdx.x;
  const int lane = tid & 63;
  const int wv = tid >> 6;
  const float inv = 1.f / NKQ;

  if (tid < 18) {
    float m = gsum1[tid] * inv;
    float var = gsum1[18 + tid] * inv - m * m;
    float sc = small[S_G1 + tid] * rsqrtf(var + 1e-5f);
    sc1s[tid] = sc; sh1s[tid] = small[S_BE1 + tid] - m * sc;
  } else if (tid >= 32 && tid < 48) {
    int c = tid - 32;
    float m = gsum2[c] * inv;
    float var = gsum2[16 + c] * inv - m * m;
    float sc = small[S_G2 + c] * rsqrtf(var + 1e-5f);
    sc2s[c] = sc; sh2s[c] = small[S_BE2 + c] - m * sc;
  }
  __syncthreads();

  const int P = blockIdx.x * 4 + wv;   // grid = 1568 -> P in [0, 6272)
  const int n = P / HWS, q = P % HWS;
  const int y = q / WID, xx = q - y * WID;

  const bool valid = lane < 49;
  const int kk = valid ? lane : 48;
  const int ki = kk / 7 - 3, kj = kk % 7 - 3;
  const int ny = refl(y + ki), nx = refl(xx + kj);
  const int nb = ny * WID + nx;
  if (valid) nbs[wv][lane] = nb;

  float t1v[18];
  {
    const float4* a4 = (const float4*)(x1t + (size_t)(n * HWS + q) * 16);
    const float4* b4 = (const float4*)(x2t + (size_t)(n * HWS + nb) * 16);
    #pragma unroll
    for (int r4 = 0; r4 < 4; r4++) {
      float4 av = a4[r4], bv = b4[r4];
      t1v[r4*4+0] = av.x - bv.x; t1v[r4*4+1] = av.y - bv.y;
      t1v[r4*4+2] = av.z - bv.z; t1v[r4*4+3] = av.w - bv.w;
    }
    float dlw = (float)(xx - nx) * (2.f / 55.f);
    float dlh = (float)(y - ny) * (2.f / 55.f);
    t1v[16] = small[S_WP+0] * dlw + small[S_WP+1] * dlh;
    t1v[17] = small[S_WP+2] * dlw + small[S_WP+3] * dlh;
  }
  #pragma unroll
  for (int c = 0; c < 18; c++)
    t1v[c] = fmaxf(fmaf(t1v[c], sc1s[c], sh1s[c]), 0.f);

  float t2v[16];
  #pragma unroll
  for (int r = 0; r < 16; r++) {
    float acc = 0.f;
    #pragma unroll
    for (int c = 0; c < 18; c++) acc = fmaf(small[S_CW1 + r * 18 + c], t1v[c], acc);
    t2v[r] = fmaxf(fmaf(acc, sc2s[r], sh2s[r]), 0.f);
  }

  // conv2 + softmax over k (across lanes); quantize ww to ushort in LDS.
  #pragma unroll
  for (int g = 0; g < 32; g++) {
    float acc = small[S_CB2 + g];
    #pragma unroll
    for (int r = 0; r < 16; r++) acc = fmaf(small[S_CW2 + g * 16 + r], t2v[r], acc);
    float e = valid ? __expf(acc) : 0.f;
    float s = e;
    #pragma unroll
    for (int off = 32; off >= 1; off >>= 1) s += __shfl_xor(s, off);
    if (valid)
      wws[wv][lane][g] = (unsigned short)__float2uint_rn(e / s * WQ);
  }
  __syncthreads();

  const short* x3p = x3i + (size_t)n * HWS * 256;
  const int* nbp = nbs[wv];
  const unsigned short (*wq)[34] = wws[wv];
  const int g0 = lane >> 3;
  float acc4[4] = {0.f, 0.f, 0.f, 0.f};
  #pragma unroll 7
  for (int k = 0; k < 49; k++) {
    const short* row = x3p + (size_t)nbp[k] * 256;
    #pragma unroll
    for (int ch = 0; ch < 4; ch++) {
      float w = (float)wq[k][ch * 8 + g0];
      acc4[ch] = fmaf(w, (float)row[ch * 64 + lane], acc4[ch]);
    }
  }
  const float osc = X3INV / WQ;
  #pragma unroll
  for (int ch = 0; ch < 4; ch++) {
    int o = ch * 64 + lane;
    outf[(size_t)(n * 256 + o) * HWS + q] = acc4[ch] * osc;   // NCHW f32
  }
}

// ---------------------------------------------------------------------------
extern "C" void kernel_launch(void* const* d_in, const int* in_sizes, int n_in,
                              void* d_out, int out_size, void* d_ws, size_t ws_size,
                              hipStream_t stream) {
  (void)in_sizes; (void)n_in; (void)out_size; (void)ws_size;
  char* ws = (char*)d_ws;
  float* gsum1 = (float*)(ws + 0);       // 36 f32
  float* gsum2 = (float*)(ws + 160);     // 32 f32
  float* small = (float*)(ws + 512);     // S_TOT f32
  float* x1t   = (float*)(ws + 4608);    // 2*3136*16 f32
  float* x2t   = (float*)(ws + 406016);  // 2*3136*16 f32
  short* x3i   = (short*)(ws + 807424);  // 2*3136*256 i16 (ends at 4018688)
  float* outf  = (float*)d_out;

  const float* x   = (const float*)d_in[0];
  const float* w1  = (const float*)d_in[1];
  const float* b1  = (const float*)d_in[2];
  const float* w2  = (const float*)d_in[3];
  const float* b2  = (const float*)d_in[4];
  const float* w3  = (const float*)d_in[5];
  const float* b3  = (const float*)d_in[6];
  const float* wp  = (const float*)d_in[7];
  const float* g1  = (const float*)d_in[9];
  const float* be1 = (const float*)d_in[10];
  const float* cw1 = (const float*)d_in[11];
  const float* g2  = (const float*)d_in[12];
  const float* be2 = (const float*)d_in[13];
  const float* cw2 = (const float*)d_in[14];
  const float* cb2 = (const float*)d_in[15];

  hipMemsetAsync(d_ws, 0, 512, stream);  // zero stat accumulators
  k_prep<<<4, 256, 0, stream>>>(cw1, cw2, cb2, wp, g1, be1, g2, be2, small);
  k_proj<<<196, 128, 0, stream>>>(x, w1, b1, w2, b2, w3, b3, x1t, x2t, x3i);
  k_stats1<<<392, 256, 0, stream>>>(x1t, x2t, small, gsum1);
  k_stats2<<<392, 256, 0, stream>>>(x1t, x2t, small, gsum1, gsum2);
  k_final<<<1568, 256, 0, stream>>>(x1t, x2t, x3i, small, gsum1, gsum2, outf);
}